// Round 15
// baseline (118.127 us; speedup 1.0000x reference)
//
#include <hip/hip_runtime.h>
#include <stdint.h>

typedef unsigned short u16;
typedef unsigned int u32;
typedef __attribute__((ext_vector_type(8))) unsigned short u16x8;
typedef __attribute__((ext_vector_type(4))) unsigned short u16x4;
typedef __attribute__((ext_vector_type(2))) unsigned int u32x2;
typedef __attribute__((ext_vector_type(4))) float f32x4;
typedef __attribute__((ext_vector_type(16))) float f32x16;
typedef __attribute__((ext_vector_type(4))) float floatx4;
typedef __attribute__((ext_vector_type(8))) __bf16 bf16x8;

// sizes: B=8, S=1024, H=768, heads=12, d=64, 3H=2304, M=B*S=8192
// ws layout (u16 elements): see previous rounds (unchanged).

__device__ __forceinline__ u16 f2bf(float f) {
  union { float f; unsigned u; } c; c.f = f;
  unsigned r = c.u + 0x7fffu + ((c.u >> 16) & 1u);   // RNE
  return (u16)(r >> 16);
}

__device__ __forceinline__ u32 packbf2(float lo, float hi) {
  return (u32)f2bf(lo) | ((u32)f2bf(hi) << 16);
}

// single-instruction packed f32->bf16 (RNE); D.lo = cvt(lo), D.hi = cvt(hi)
__device__ __forceinline__ u32 cvtpk(float lo, float hi) {
  u32 r;
  asm("v_cvt_pk_bf16_f32 %0, %1, %2" : "=v"(r) : "v"(lo), "v"(hi));
  return r;
}

__device__ __forceinline__ bf16x8 ld_bf8(const u16* p) {
  return __builtin_bit_cast(bf16x8, *(const u16x8*)p);
}

__device__ __forceinline__ float fexp2(float x) {
#if __has_builtin(__builtin_amdgcn_exp2f)
  return __builtin_amdgcn_exp2f(x);
#else
  float r; asm("v_exp_f32 %0, %1" : "=v"(r) : "v"(x)); return r;
#endif
}

// async global->LDS, 16 B per lane; LDS dest = wave-uniform base + lane*16
__device__ __forceinline__ void glds16(const void* g, void* l) {
  __builtin_amdgcn_global_load_lds(
      (const __attribute__((address_space(1))) void*)g,
      (__attribute__((address_space(3))) void*)l, 16, 0, 0);
}

// ---------------------------------------------------------------- convert
__global__ void convert_kernel(const float* __restrict__ x,
                               const float* __restrict__ w1,
                               const float* __restrict__ w2,
                               u16* __restrict__ xb,
                               u16* __restrict__ w1b,
                               u16* __restrict__ w2b) {
  const long NX = 6291456 / 4, NW1 = 1769472 / 4, NW2 = 589824 / 4;
  const long total = NX + NW1 + NW2;
  for (long i = (long)blockIdx.x * 256 + threadIdx.x; i < total;
       i += (long)gridDim.x * 256) {
    const float* src; u16* dst; long j;
    if (i < NX)            { src = x;  dst = xb;  j = i; }
    else if (i < NX + NW1) { src = w1; dst = w1b; j = i - NX; }
    else                   { src = w2; dst = w2b; j = i - NX - NW1; }
    floatx4 v = ((const floatx4*)src)[j];
    u16x4 o;
    o[0] = f2bf(v[0]); o[1] = f2bf(v[1]); o[2] = f2bf(v[2]); o[3] = f2bf(v[3]);
    ((u16x4*)dst)[j] = o;
  }
}

// ---------------------------------------------------------------- QKV GEMM
// BM=128, BN=192, BK=32, 4 waves, 3-deep staged LDS, counted vmcnt,
// macro-row-paired swizzle, per-head epilogue (R10, verified).
__global__ __launch_bounds__(256, 2)
void qkv_gemm(const u16* __restrict__ A, const u16* __restrict__ W,
              const float* __restrict__ bias,
              u16* __restrict__ qb, u16* __restrict__ kb, u16* __restrict__ vtb) {
  __shared__ __align__(16) u16 lds[30720];   // 60 KB: A 3x4096, B 3x6144
  const int tid = threadIdx.x;
  const int lane = tid & 63, wid = tid >> 6;
  const int wm = wid >> 1, wn = wid & 1;
  const int l15 = lane & 15, l4 = lane >> 4;

  const int p = blockIdx.x;                  // 768 = 8 * 96
  const int xcd = p & 7, i = p >> 3;
  const int by = xcd * 8 + i / 12;
  const int bx = i % 12;
  const int rowA0 = by * 128, rowB0 = bx * 192;

  const int rlo = lane >> 3;
  const u16* gA[2];
  const u16* gB[3];
#pragma unroll
  for (int c = 0; c < 2; ++c) {
    int mr = wid * 16 + c * 8 + rlo;
    int sl = (lane & 7) ^ (mr & 7);
    gA[c] = A + (size_t)(rowA0 + 2 * mr + (sl >> 2)) * 768 + (sl & 3) * 8;
  }
#pragma unroll
  for (int c = 0; c < 3; ++c) {
    int mr = wid * 24 + c * 8 + rlo;
    int sl = (lane & 7) ^ (mr & 7);
    gB[c] = W + (size_t)(rowB0 + 2 * mr + (sl >> 2)) * 768 + (sl & 3) * 8;
  }

  f32x4 acc[4][6];
  const f32x4 vz = {0.f, 0.f, 0.f, 0.f};
#pragma unroll
  for (int mi = 0; mi < 4; ++mi)
#pragma unroll
    for (int nj = 0; nj < 6; ++nj) acc[mi][nj] = vz;

#define QSTAGE(kb_, k0_)                                                   \
  {                                                                        \
    u16* bA_ = lds + (kb_) * 4096;                                         \
    u16* bB_ = lds + 12288 + (kb_) * 6144;                                 \
    _Pragma("unroll") for (int c = 0; c < 2; ++c)                          \
        glds16(gA[c] + (k0_), bA_ + (wid * 16 + c * 8) * 64);              \
    _Pragma("unroll") for (int c = 0; c < 3; ++c)                          \
        glds16(gB[c] + (k0_), bB_ + (wid * 24 + c * 8) * 64);              \
  }

  QSTAGE(0, 0);
  QSTAGE(1, 32);

  for (int ks = 0; ks < 24; ++ks) {
    const int cb = ks % 3;
    const u16* cA = lds + cb * 4096;
    const u16* cB = lds + 12288 + cb * 6144;

    __builtin_amdgcn_s_barrier();
    if (ks < 22) {
      QSTAGE((ks + 2) % 3, (ks + 2) * 32);
      asm volatile("s_waitcnt vmcnt(10)" ::: "memory");
    } else if (ks == 22) {
      asm volatile("s_waitcnt vmcnt(5)" ::: "memory");
    } else {
      asm volatile("s_waitcnt vmcnt(0)" ::: "memory");
    }
    __builtin_amdgcn_s_barrier();
    __builtin_amdgcn_sched_barrier(0);

    bf16x8 af[4], bfr[6];
#pragma unroll
    for (int mi = 0; mi < 4; ++mi) {
      int m = wm * 64 + mi * 16 + l15;
      int mr = m >> 1;
      int sp = ((m & 1) * 4 + l4) ^ (mr & 7);
      af[mi] = ld_bf8(cA + mr * 64 + sp * 8);
    }
#pragma unroll
    for (int nj = 0; nj < 6; ++nj) {
      int n = wn * 96 + nj * 16 + l15;
      int mr = n >> 1;
      int sp = ((n & 1) * 4 + l4) ^ (mr & 7);
      bfr[nj] = ld_bf8(cB + mr * 64 + sp * 8);
    }
    __builtin_amdgcn_s_setprio(1);
#pragma unroll
    for (int mi = 0; mi < 4; ++mi)
#pragma unroll
      for (int nj = 0; nj < 6; ++nj)
        acc[mi][nj] = __builtin_amdgcn_mfma_f32_16x16x32_bf16(
            af[mi], bfr[nj], acc[mi][nj], 0, 0, 0);
    __builtin_amdgcn_s_setprio(0);
  }
#undef QSTAGE

  const float QSC = 0.125f * 1.44269504088896f;
  const int batch = by >> 3, s0 = (by & 7) * 128;
  const size_t gbase = (size_t)(batch * 12 + bx) * 65536;

  float bias_v[6];
#pragma unroll
  for (int nj = 0; nj < 6; ++nj)
    bias_v[nj] = bias[rowB0 + wn * 96 + nj * 16 + l15];

  __syncthreads();

#pragma unroll
  for (int nj = 0; nj < 6; ++nj) {
    int col0 = wn * 96 + nj * 16;
    int band = col0 >> 6;
    int dd = (col0 & 63) + l15;
    float bv = bias_v[nj];
    if (band < 2) {
      float sc = (band == 0) ? QSC : 1.0f;
      u16* reg = lds + band * 9216;
#pragma unroll
      for (int mi = 0; mi < 4; ++mi)
#pragma unroll
        for (int r = 0; r < 4; ++r) {
          int m = wm * 64 + mi * 16 + l4 * 4 + r;
          reg[m * 72 + dd] = f2bf((acc[mi][nj][r] + bv) * sc);
        }
    } else {
      u16* reg = lds + 18432;
#pragma unroll
      for (int mi = 0; mi < 4; ++mi)
#pragma unroll
        for (int r = 0; r < 4; r += 2) {
          int m = wm * 64 + mi * 16 + l4 * 4 + r;
          *(u32*)&reg[dd * 136 + m] =
              packbf2(acc[mi][nj][r] + bv, acc[mi][nj][r + 1] + bv);
        }
    }
  }
  __syncthreads();

#pragma unroll
  for (int j = 0; j < 4; ++j) {
    int c = tid + j * 256;
    int m = c >> 3, dd0 = (c & 7) << 3;
    u16x8 v = *(const u16x8*)&lds[m * 72 + dd0];
    *(u16x8*)&qb[gbase + (size_t)(s0 + m) * 64 + dd0] = v;
  }
#pragma unroll
  for (int j = 0; j < 4; ++j) {
    int c = tid + j * 256;
    int m = c >> 3, dd0 = (c & 7) << 3;
    u16x8 v = *(const u16x8*)&lds[9216 + m * 72 + dd0];
    *(u16x8*)&kb[gbase + (size_t)(s0 + m) * 64 + dd0] = v;
  }
#pragma unroll
  for (int j = 0; j < 4; ++j) {
    int c = tid + j * 256;
    int dd = c >> 4, m0 = (c & 15) << 3;
    u16x8 v = *(const u16x8*)&lds[18432 + dd * 136 + m0];
    *(u16x8*)&vtb[gbase + (size_t)dd * 1024 + s0 + m0] = v;
  }
}

// ---------------------------------------------------------------- attention
// grid (96, 4), 256 threads = 4 waves; wave w owns 64 q-rows as two 32-row
// halves sharing one K-frag and one V-frag register set per kk (40% fewer
// LDS fragment reads per row; block staging amortized over 256 rows = half
// the LDS-write traffic). plds reused sequentially by the halves
// (wave-private in-order DS, same pattern as R10's kk reuse).
__global__ __launch_bounds__(256, 2)
void attn_kernel(const u16* __restrict__ qb, const u16* __restrict__ kb,
                 const u16* __restrict__ vtb, const void* __restrict__ maskp,
                 u16* __restrict__ x2) {
  const int bh = blockIdx.x, qt = blockIdx.y;
  const int b = bh / 12, h = bh - b * 12;
  const int tid = threadIdx.x;
  const int w = tid >> 6, lane = tid & 63;
  const int l31 = lane & 31, hi = lane >> 5;

  __shared__ float mbias[1024];                   // 4 KB additive bias table
  __shared__ int any_big;
  __shared__ __align__(16) u16 plds[4][32][40];   // 10 KB per-wave P^T buffer
  __shared__ __align__(16) u16 kvs[16384];        // 32 KB: [buf][K|V][64][64]

  // ---- mask -> additive exp2-domain bias (robust to int32 vs byte bool) ----
  if (tid == 0) any_big = 0;
  __syncthreads();
  {
    const unsigned* mu = (const unsigned*)maskp;
    int loc = 0;
    for (int i = tid; i < 2048; i += 256)
      if (mu[i] > 1u) loc = 1;
    if (loc) atomicOr(&any_big, 1);
  }
  __syncthreads();
  const float CEXP = 23.0831206542234f;  // 16 * log2(e)
  if (any_big) {
    const unsigned char* mb = (const unsigned char*)maskp;
    for (int i = tid; i < 1024; i += 256)
      mbias[i] = mb[b * 1024 + i] ? -100000.0f : -CEXP;
  } else {
    const int* mi_ = (const int*)maskp;
    for (int i = tid; i < 1024; i += 256)
      mbias[i] = mi_[b * 1024 + i] ? -100000.0f : -CEXP;
  }

  const size_t base = (size_t)bh * 65536;
  const int q0w = qt * 256 + w * 64;

  // staging geometry (R10-verified): thread stages rows srow and srow+32;
  // global 16B-col pre-swizzled by row&7 -> LDS[row][sl] = G[row][sl^(row&7)]
  const int rlo = lane >> 3;
  const int cg = (lane & 7) ^ (rlo & 7);          // (w*8+rlo)&7 == rlo&7
  const int srow = w * 8 + rlo;
  const u16* kg0 = kb + base + (size_t)srow * 64 + cg * 8;     // + kt*4096
  const u16* vg0 = vtb + base + (size_t)srow * 1024 + cg * 8;  // + kt*64
  u16* kd0 = kvs + w * 512;                        // + buf*8192
  u16* vd0 = kvs + 4096 + w * 512;                 // + buf*8192

  // Q as B-fragments for both 32-row halves
  bf16x8 qf0[4], qf1[4];
#pragma unroll
  for (int ds = 0; ds < 4; ++ds) {
    qf0[ds] = ld_bf8(qb + base + (size_t)(q0w + l31) * 64 + ds * 16 + hi * 8);
    qf1[ds] = ld_bf8(qb + base + (size_t)(q0w + 32 + l31) * 64 + ds * 16 + hi * 8);
  }

  f32x16 o0[2], o1[2];   // O^T accum per half
#pragma unroll
  for (int dh = 0; dh < 2; ++dh)
#pragma unroll
    for (int r = 0; r < 16; ++r) { o0[dh][r] = 0.f; o1[dh][r] = 0.f; }
  float ps0 = 0.f, ps1 = 0.f;

  // prologue: stage tile 0 into buffer 0
  glds16(kg0, kd0);
  glds16(kg0 + 32 * 64, kd0 + 2048);
  glds16(vg0, vd0);
  glds16(vg0 + 32 * 1024, vd0 + 2048);
  __syncthreads();

// softmax + PV for one half: SV = scores, OD = O accum, PS = row-sum
#define SMPV(SV, OD, PS)                                                     \
  {                                                                          \
    _Pragma("unroll") for (int g = 0; g < 4; ++g) {                          \
      f32x4 bv = *(const f32x4*)(mbias + kt * 64 + kk * 32 + g * 8 + hi * 4);\
      float p0 = fexp2(SV[g * 4 + 0] + bv[0]);                               \
      float p1 = fexp2(SV[g * 4 + 1] + bv[1]);                               \
      float p2 = fexp2(SV[g * 4 + 2] + bv[2]);                               \
      float p3 = fexp2(SV[g * 4 + 3] + bv[3]);                               \
      PS += (p0 + p1) + (p2 + p3);                                           \
      const int colb = g * 8 + hi * 4;                                       \
      *(u32*)&plds[w][l31][colb]     = cvtpk(p0, p1);                        \
      *(u32*)&plds[w][l31][colb + 2] = cvtpk(p2, p3);                        \
    }                                                                        \
    __builtin_amdgcn_s_setprio(1);                                           \
    _Pragma("unroll") for (int t = 0; t < 2; ++t) {                          \
      bf16x8 pf = ld_bf8(&plds[w][l31][t * 16 + hi * 8]);                    \
      _Pragma("unroll") for (int dh = 0; dh < 2; ++dh)                       \
        OD[dh] = __builtin_amdgcn_mfma_f32_32x32x16_bf16(vf[t][dh], pf,      \
                                                         OD[dh], 0, 0, 0);   \
    }                                                                        \
    __builtin_amdgcn_s_setprio(0);                                           \
  }

  for (int kt = 0; kt < 16; ++kt) {
    const int cur = kt & 1;
    if (kt < 15) {   // async prefetch next tile into the other buffer
      const int nxt = cur ^ 1;
      glds16(kg0 + (kt + 1) * 4096, kd0 + nxt * 8192);
      glds16(kg0 + (kt + 1) * 4096 + 32 * 64, kd0 + nxt * 8192 + 2048);
      glds16(vg0 + (kt + 1) * 64, vd0 + nxt * 8192);
      glds16(vg0 + (kt + 1) * 64 + 32 * 1024, vd0 + nxt * 8192 + 2048);
    }

    const u16* Kl = kvs + cur * 8192;
    const u16* Vl = kvs + cur * 8192 + 4096;

#pragma unroll
    for (int kk = 0; kk < 2; ++kk) {
      const int rk = kk * 32 + l31;
      // K fragments once, shared by both q-halves
      bf16x8 kf[4];
#pragma unroll
      for (int ds = 0; ds < 4; ++ds)
        kf[ds] = ld_bf8(Kl + rk * 64 + ((ds * 2 + hi) ^ (rk & 7)) * 8);

      f32x16 s0, s1;
#pragma unroll
      for (int r = 0; r < 16; ++r) { s0[r] = 0.f; s1[r] = 0.f; }
      __builtin_amdgcn_s_setprio(1);
#pragma unroll
      for (int ds = 0; ds < 4; ++ds)
        s0 = __builtin_amdgcn_mfma_f32_32x32x16_bf16(kf[ds], qf0[ds], s0, 0, 0, 0);
#pragma unroll
      for (int ds = 0; ds < 4; ++ds)
        s1 = __builtin_amdgcn_mfma_f32_32x32x16_bf16(kf[ds], qf1[ds], s1, 0, 0, 0);
      __builtin_amdgcn_s_setprio(0);

      // V fragments once, shared by both q-halves
      bf16x8 vf[2][2];
#pragma unroll
      for (int t = 0; t < 2; ++t)
#pragma unroll
        for (int dh = 0; dh < 2; ++dh) {
          const int rv = dh * 32 + l31;
          const int gv = kk * 4 + t * 2 + hi;
          vf[t][dh] = ld_bf8(Vl + rv * 64 + (gv ^ (rv & 7)) * 8);
        }

      SMPV(s0, o0, ps0);   // half 0: writes plds, reads pf, PV
      SMPV(s1, o1, ps1);   // half 1: overwrites plds after half0's reads
    }

    __syncthreads();   // staged kt+1 complete; safe to swap buffers
  }
#undef SMPV

  // row sums: combine hi halves
  ps0 += __shfl_xor(ps0, 32, 64);
  ps1 += __shfl_xor(ps1, 32, 64);
  float inv0 = 1.0f / ps0, inv1 = 1.0f / ps1;

  // epilogue per half: stage bf16 O^T into kvs (free now), vector-store
  u16* obuf = kvs + w * 2304;   // [32][72] per wave
#pragma unroll
  for (int half = 0; half < 2; ++half) {
    const f32x16* oh = half ? o1 : o0;
    float inv = half ? inv1 : inv0;
#pragma unroll
    for (int dh = 0; dh < 2; ++dh)
#pragma unroll
      for (int j = 0; j < 8; ++j) {
        u32 v = cvtpk(oh[dh][2 * j] * inv, oh[dh][2 * j + 1] * inv);
        int col = dh * 32 + 8 * (j >> 1) + 4 * hi + 2 * (j & 1);
        *(u32*)(obuf + l31 * 72 + col) = v;
      }
    {
      int row2 = lane >> 1, ch = lane & 1;
      const u16* srcp = obuf + row2 * 72 + ch * 32;
      u16x8 t0 = *(const u16x8*)(srcp);
      u16x8 t1 = *(const u16x8*)(srcp + 8);
      u16x8 t2 = *(const u16x8*)(srcp + 16);
      u16x8 t3 = *(const u16x8*)(srcp + 24);
      size_t m = (size_t)b * 1024 + q0w + half * 32 + row2;
      u16* dst = x2 + m * 768 + h * 64 + ch * 32;
      *(u16x8*)dst = t0;
      *(u16x8*)(dst + 8) = t1;
      *(u16x8*)(dst + 16) = t2;
      *(u16x8*)(dst + 24) = t3;
    }
  }
}

// ---------------------------------------------------------------- out proj
// BM=64, BN=192, BK=32, 4 waves, 3-deep counted vmcnt, macro-row-paired
// swizzle; fp32 epilogue. Grid 512 = 8 XCD x (16 by x 4 bx) (R14).
__global__ __launch_bounds__(256, 2)
void out_gemm(const u16* __restrict__ A, const u16* __restrict__ W,
              const float* __restrict__ bias, float* __restrict__ out) {
  __shared__ __align__(16) u16 lds[24576];   // 48 KB: A 3x2048, B 3x6144
  const int tid = threadIdx.x;
  const int lane = tid & 63, wid = tid >> 6;
  const int wm = wid >> 1, wn = wid & 1;
  const int l15 = lane & 15, l4 = lane >> 4;

  const int p = blockIdx.x;                  // 512 = 8 * 64
  const int xcd = p & 7, i = p >> 3;
  const int by = xcd * 16 + (i >> 2);
  const int bx = i & 3;
  const int rowA0 = by * 64, rowB0 = bx * 192;

  const int rlo = lane >> 3;
  const u16* gA0;
  {
    int mr = wid * 8 + rlo;
    int sl = (lane & 7) ^ (mr & 7);
    gA0 = A + (size_t)(rowA0 + 2 * mr + (sl >> 2)) * 768 + (sl & 3) * 8;
  }
  const u16* gB[3];
#pragma unroll
  for (int c = 0; c < 3; ++c) {
    int mr = wid * 24 + c * 8 + rlo;
    int sl = (lane & 7) ^ (mr & 7);
    gB[c] = W + (size_t)(rowB0 + 2 * mr + (sl >> 2)) * 768 + (sl & 3) * 8;
  }

  f32x4 acc[2][6];
  const f32x4 vz = {0.f, 0.f, 0.f, 0.f};
#pragma unroll
  for (int mi = 0; mi < 2; ++mi)
#pragma unroll
    for (int nj = 0; nj < 6; ++nj) acc[mi][nj] = vz;

#define OSTAGE(kb_, k0_)                                                   \
  {                                                                        \
    u16* bA_ = lds + (kb_) * 2048;                                         \
    u16* bB_ = lds + 6144 + (kb_) * 6144;                                  \
    glds16(gA0 + (k0_), bA_ + (wid * 8) * 64);                             \
    _Pragma("unroll") for (int c = 0; c < 3; ++c)                          \
        glds16(gB[c] + (k0_), bB_ + (wid * 24 + c * 8) * 64);              \
  }

  OSTAGE(0, 0);
  OSTAGE(1, 32);

  for (int ks = 0; ks < 24; ++ks) {
    const int cb = ks % 3;
    const u16* cA = lds + cb * 2048;
    const u16* cB = lds + 6144 + cb * 6144;

    __builtin_amdgcn_s_barrier();
    if (ks < 22) {
      OSTAGE((ks + 2) % 3, (ks + 2) * 32);
      asm volatile("s_waitcnt vmcnt(8)" ::: "memory");
    } else if (ks == 22) {
      asm volatile("s_waitcnt vmcnt(4)" ::: "memory");
    } else {
      asm volatile("s_waitcnt vmcnt(0)" ::: "memory");
    }
    __builtin_amdgcn_s_barrier();
    __builtin_amdgcn_sched_barrier(0);

    bf16x8 af[2], bfr[6];
#pragma unroll
    for (int mi = 0; mi < 2; ++mi) {
      int m = wm * 32 + mi * 16 + l15;
      int mr = m >> 1;
      int sp = ((m & 1) * 4 + l4) ^ (mr & 7);
      af[mi] = ld_bf8(cA + mr * 64 + sp * 8);
    }
#pragma unroll
    for (int nj = 0; nj < 6; ++nj) {
      int n = wn * 96 + nj * 16 + l15;
      int mr = n >> 1;
      int sp = ((n & 1) * 4 + l4) ^ (mr & 7);
      bfr[nj] = ld_bf8(cB + mr * 64 + sp * 8);
    }
    __builtin_amdgcn_s_setprio(1);
#pragma unroll
    for (int mi = 0; mi < 2; ++mi)
#pragma unroll
      for (int nj = 0; nj < 6; ++nj)
        acc[mi][nj] = __builtin_amdgcn_mfma_f32_16x16x32_bf16(
            af[mi], bfr[nj], acc[mi][nj], 0, 0, 0);
    __builtin_amdgcn_s_setprio(0);
  }
#undef OSTAGE

#pragma unroll
  for (int nj = 0; nj < 6; ++nj) {
    int n = rowB0 + wn * 96 + nj * 16 + l15;
    float bn_ = bias[n];
#pragma unroll
    for (int mi = 0; mi < 2; ++mi)
#pragma unroll
      for (int r = 0; r < 4; ++r) {
        int m = rowA0 + wm * 32 + mi * 16 + l4 * 4 + r;
        out[(size_t)m * 768 + n] = acc[mi][nj][r] + bn_;
      }
  }
}

// ---------------------------------------------------------------- launch
extern "C" void kernel_launch(void* const* d_in, const int* in_sizes, int n_in,
                              void* d_out, int out_size, void* d_ws, size_t ws_size,
                              hipStream_t stream) {
  const float* x    = (const float*)d_in[0];
  const void*  mask = d_in[1];
  const float* wqkv = (const float*)d_in[2];
  const float* bqkv = (const float*)d_in[3];
  const float* wo   = (const float*)d_in[4];
  const float* bo   = (const float*)d_in[5];
  float* out = (float*)d_out;

  u16* ws = (u16*)d_ws;
  u16* xbf   = ws;
  u16* wqkvb = ws + 6291456;
  u16* wob   = ws + 8060928;
  u16* qbuf  = ws + 8650752;
  u16* kbuf  = ws + 14942208;
  u16* vtbuf = ws + 21233664;
  u16* x2buf = ws + 27525120;

  convert_kernel<<<2048, 256, 0, stream>>>(x, wqkv, wo, xbf, wqkvb, wob);
  qkv_gemm<<<768, 256, 0, stream>>>(xbf, wqkvb, bqkv, qbuf, kbuf, vtbuf);
  attn_kernel<<<dim3(96, 4), 256, 0, stream>>>(qbuf, kbuf, vtbuf, mask, x2buf);
  out_gemm<<<512, 256, 0, stream>>>(x2buf, wob, bo, out);
}

// Round 17
// 111.828 us; speedup vs baseline: 1.0563x; 1.0563x over previous
//
#include <hip/hip_runtime.h>
#include <stdint.h>

typedef unsigned short u16;
typedef unsigned int u32;
typedef __attribute__((ext_vector_type(8))) unsigned short u16x8;
typedef __attribute__((ext_vector_type(4))) unsigned short u16x4;
typedef __attribute__((ext_vector_type(4))) float f32x4;
typedef __attribute__((ext_vector_type(16))) float f32x16;
typedef __attribute__((ext_vector_type(4))) float floatx4;
typedef __attribute__((ext_vector_type(8))) __bf16 bf16x8;

// sizes: B=8, S=1024, H=768, heads=12, d=64, 3H=2304, M=B*S=8192
// ws layout (u16 elements): see previous rounds (unchanged).

__device__ __forceinline__ u16 f2bf(float f) {
  union { float f; unsigned u; } c; c.f = f;
  unsigned r = c.u + 0x7fffu + ((c.u >> 16) & 1u);   // RNE
  return (u16)(r >> 16);
}

__device__ __forceinline__ u32 packbf2(float lo, float hi) {
  return (u32)f2bf(lo) | ((u32)f2bf(hi) << 16);
}

// single-instruction packed f32->bf16 (RNE); D.lo = cvt(lo), D.hi = cvt(hi)
__device__ __forceinline__ u32 cvtpk(float lo, float hi) {
  u32 r;
  asm("v_cvt_pk_bf16_f32 %0, %1, %2" : "=v"(r) : "v"(lo), "v"(hi));
  return r;
}

__device__ __forceinline__ bf16x8 ld_bf8(const u16* p) {
  return __builtin_bit_cast(bf16x8, *(const u16x8*)p);
}

__device__ __forceinline__ float fexp2(float x) {
#if __has_builtin(__builtin_amdgcn_exp2f)
  return __builtin_amdgcn_exp2f(x);
#else
  float r; asm("v_exp_f32 %0, %1" : "=v"(r) : "v"(x)); return r;
#endif
}

// async global->LDS, 16 B per lane; LDS dest = wave-uniform base + lane*16
__device__ __forceinline__ void glds16(const void* g, void* l) {
  __builtin_amdgcn_global_load_lds(
      (const __attribute__((address_space(1))) void*)g,
      (__attribute__((address_space(3))) void*)l, 16, 0, 0);
}

// ---------------------------------------------------------------- convert
__global__ void convert_kernel(const float* __restrict__ x,
                               const float* __restrict__ w1,
                               const float* __restrict__ w2,
                               u16* __restrict__ xb,
                               u16* __restrict__ w1b,
                               u16* __restrict__ w2b) {
  const long NX = 6291456 / 4, NW1 = 1769472 / 4, NW2 = 589824 / 4;
  const long total = NX + NW1 + NW2;
  for (long i = (long)blockIdx.x * 256 + threadIdx.x; i < total;
       i += (long)gridDim.x * 256) {
    const float* src; u16* dst; long j;
    if (i < NX)            { src = x;  dst = xb;  j = i; }
    else if (i < NX + NW1) { src = w1; dst = w1b; j = i - NX; }
    else                   { src = w2; dst = w2b; j = i - NX - NW1; }
    floatx4 v = ((const floatx4*)src)[j];
    u16x4 o;
    o[0] = f2bf(v[0]); o[1] = f2bf(v[1]); o[2] = f2bf(v[2]); o[3] = f2bf(v[3]);
    ((u16x4*)dst)[j] = o;
  }
}

// ---------------------------------------------------------------- QKV GEMM
// BM=128, BN=192, BK=32, 4 waves, 3-deep staged LDS, counted vmcnt,
// macro-row-paired swizzle, per-head epilogue (R10, verified).
__global__ __launch_bounds__(256, 2)
void qkv_gemm(const u16* __restrict__ A, const u16* __restrict__ W,
              const float* __restrict__ bias,
              u16* __restrict__ qb, u16* __restrict__ kb, u16* __restrict__ vtb) {
  __shared__ __align__(16) u16 lds[30720];   // 60 KB: A 3x4096, B 3x6144
  const int tid = threadIdx.x;
  const int lane = tid & 63, wid = tid >> 6;
  const int wm = wid >> 1, wn = wid & 1;
  const int l15 = lane & 15, l4 = lane >> 4;

  const int p = blockIdx.x;                  // 768 = 8 * 96
  const int xcd = p & 7, i = p >> 3;
  const int by = xcd * 8 + i / 12;
  const int bx = i % 12;
  const int rowA0 = by * 128, rowB0 = bx * 192;

  const int rlo = lane >> 3;
  const u16* gA[2];
  const u16* gB[3];
#pragma unroll
  for (int c = 0; c < 2; ++c) {
    int mr = wid * 16 + c * 8 + rlo;
    int sl = (lane & 7) ^ (mr & 7);
    gA[c] = A + (size_t)(rowA0 + 2 * mr + (sl >> 2)) * 768 + (sl & 3) * 8;
  }
#pragma unroll
  for (int c = 0; c < 3; ++c) {
    int mr = wid * 24 + c * 8 + rlo;
    int sl = (lane & 7) ^ (mr & 7);
    gB[c] = W + (size_t)(rowB0 + 2 * mr + (sl >> 2)) * 768 + (sl & 3) * 8;
  }

  f32x4 acc[4][6];
  const f32x4 vz = {0.f, 0.f, 0.f, 0.f};
#pragma unroll
  for (int mi = 0; mi < 4; ++mi)
#pragma unroll
    for (int nj = 0; nj < 6; ++nj) acc[mi][nj] = vz;

#define QSTAGE(kb_, k0_)                                                   \
  {                                                                        \
    u16* bA_ = lds + (kb_) * 4096;                                         \
    u16* bB_ = lds + 12288 + (kb_) * 6144;                                 \
    _Pragma("unroll") for (int c = 0; c < 2; ++c)                          \
        glds16(gA[c] + (k0_), bA_ + (wid * 16 + c * 8) * 64);              \
    _Pragma("unroll") for (int c = 0; c < 3; ++c)                          \
        glds16(gB[c] + (k0_), bB_ + (wid * 24 + c * 8) * 64);              \
  }

  QSTAGE(0, 0);
  QSTAGE(1, 32);

  for (int ks = 0; ks < 24; ++ks) {
    const int cb = ks % 3;
    const u16* cA = lds + cb * 4096;
    const u16* cB = lds + 12288 + cb * 6144;

    __builtin_amdgcn_s_barrier();
    if (ks < 22) {
      QSTAGE((ks + 2) % 3, (ks + 2) * 32);
      asm volatile("s_waitcnt vmcnt(10)" ::: "memory");
    } else if (ks == 22) {
      asm volatile("s_waitcnt vmcnt(5)" ::: "memory");
    } else {
      asm volatile("s_waitcnt vmcnt(0)" ::: "memory");
    }
    __builtin_amdgcn_s_barrier();
    __builtin_amdgcn_sched_barrier(0);

    bf16x8 af[4], bfr[6];
#pragma unroll
    for (int mi = 0; mi < 4; ++mi) {
      int m = wm * 64 + mi * 16 + l15;
      int mr = m >> 1;
      int sp = ((m & 1) * 4 + l4) ^ (mr & 7);
      af[mi] = ld_bf8(cA + mr * 64 + sp * 8);
    }
#pragma unroll
    for (int nj = 0; nj < 6; ++nj) {
      int n = wn * 96 + nj * 16 + l15;
      int mr = n >> 1;
      int sp = ((n & 1) * 4 + l4) ^ (mr & 7);
      bfr[nj] = ld_bf8(cB + mr * 64 + sp * 8);
    }
    __builtin_amdgcn_s_setprio(1);
#pragma unroll
    for (int mi = 0; mi < 4; ++mi)
#pragma unroll
      for (int nj = 0; nj < 6; ++nj)
        acc[mi][nj] = __builtin_amdgcn_mfma_f32_16x16x32_bf16(
            af[mi], bfr[nj], acc[mi][nj], 0, 0, 0);
    __builtin_amdgcn_s_setprio(0);
  }
#undef QSTAGE

  const float QSC = 0.125f * 1.44269504088896f;
  const int batch = by >> 3, s0 = (by & 7) * 128;
  const size_t gbase = (size_t)(batch * 12 + bx) * 65536;

  float bias_v[6];
#pragma unroll
  for (int nj = 0; nj < 6; ++nj)
    bias_v[nj] = bias[rowB0 + wn * 96 + nj * 16 + l15];

  __syncthreads();

#pragma unroll
  for (int nj = 0; nj < 6; ++nj) {
    int col0 = wn * 96 + nj * 16;
    int band = col0 >> 6;
    int dd = (col0 & 63) + l15;
    float bv = bias_v[nj];
    if (band < 2) {
      float sc = (band == 0) ? QSC : 1.0f;
      u16* reg = lds + band * 9216;
#pragma unroll
      for (int mi = 0; mi < 4; ++mi)
#pragma unroll
        for (int r = 0; r < 4; ++r) {
          int m = wm * 64 + mi * 16 + l4 * 4 + r;
          reg[m * 72 + dd] = f2bf((acc[mi][nj][r] + bv) * sc);
        }
    } else {
      u16* reg = lds + 18432;
#pragma unroll
      for (int mi = 0; mi < 4; ++mi)
#pragma unroll
        for (int r = 0; r < 4; r += 2) {
          int m = wm * 64 + mi * 16 + l4 * 4 + r;
          *(u32*)&reg[dd * 136 + m] =
              packbf2(acc[mi][nj][r] + bv, acc[mi][nj][r + 1] + bv);
        }
    }
  }
  __syncthreads();

#pragma unroll
  for (int j = 0; j < 4; ++j) {
    int c = tid + j * 256;
    int m = c >> 3, dd0 = (c & 7) << 3;
    u16x8 v = *(const u16x8*)&lds[m * 72 + dd0];
    *(u16x8*)&qb[gbase + (size_t)(s0 + m) * 64 + dd0] = v;
  }
#pragma unroll
  for (int j = 0; j < 4; ++j) {
    int c = tid + j * 256;
    int m = c >> 3, dd0 = (c & 7) << 3;
    u16x8 v = *(const u16x8*)&lds[9216 + m * 72 + dd0];
    *(u16x8*)&kb[gbase + (size_t)(s0 + m) * 64 + dd0] = v;
  }
#pragma unroll
  for (int j = 0; j < 4; ++j) {
    int c = tid + j * 256;
    int dd = c >> 4, m0 = (c & 15) << 3;
    u16x8 v = *(const u16x8*)&lds[18432 + dd * 136 + m0];
    *(u16x8*)&vtb[gbase + (size_t)dd * 1024 + s0 + m0] = v;
  }
}

// ---------------------------------------------------------------- attention
// grid (96, 8), 256 threads = 4 waves, 3 blocks/CU (LDS ~47 KB).
// R13 exact (best measured attn: 52.3 us): swapped-32x32 compute + async
// double-buffered coalesced K/V staging; cvt_pk for bf16 packing; plds
// P-roundtrip (permlane path retired after two failures).
__global__ __launch_bounds__(256, 3)
void attn_kernel(const u16* __restrict__ qb, const u16* __restrict__ kb,
                 const u16* __restrict__ vtb, const void* __restrict__ maskp,
                 u16* __restrict__ x2) {
  const int bh = blockIdx.x, qt = blockIdx.y;
  const int b = bh / 12, h = bh - b * 12;
  const int tid = threadIdx.x;
  const int w = tid >> 6, lane = tid & 63;
  const int l31 = lane & 31, hi = lane >> 5;

  __shared__ float mbias[1024];                   // 4 KB additive bias table
  __shared__ int any_big;
  __shared__ __align__(16) u16 plds[4][32][40];   // 10 KB per-kk P^T buffers
  __shared__ __align__(16) u16 kvs[16384];        // 32 KB: [buf][K|V][64][64]

  // ---- mask -> additive exp2-domain bias (robust to int32 vs byte bool) ----
  if (tid == 0) any_big = 0;
  __syncthreads();
  {
    const unsigned* mu = (const unsigned*)maskp;
    int loc = 0;
    for (int i = tid; i < 2048; i += 256)
      if (mu[i] > 1u) loc = 1;
    if (loc) atomicOr(&any_big, 1);
  }
  __syncthreads();
  const float CEXP = 23.0831206542234f;  // 16 * log2(e)
  if (any_big) {
    const unsigned char* mb = (const unsigned char*)maskp;
    for (int i = tid; i < 1024; i += 256)
      mbias[i] = mb[b * 1024 + i] ? -100000.0f : -CEXP;
  } else {
    const int* mi_ = (const int*)maskp;
    for (int i = tid; i < 1024; i += 256)
      mbias[i] = mi_[b * 1024 + i] ? -100000.0f : -CEXP;
  }

  const size_t base = (size_t)bh * 65536;
  const int q0w = qt * 128 + w * 32;

  // staging geometry: thread stages rows srow and srow+32 (16B each);
  // global 16B-col pre-swizzled by row&7 -> LDS[row][sl] = G[row][sl^(row&7)]
  const int rlo = lane >> 3;
  const int cg = (lane & 7) ^ (rlo & 7);          // (w*8+rlo)&7 == rlo&7
  const int srow = w * 8 + rlo;
  const u16* kg0 = kb + base + (size_t)srow * 64 + cg * 8;     // + kt*4096
  const u16* vg0 = vtb + base + (size_t)srow * 1024 + cg * 8;  // + kt*64
  u16* kd0 = kvs + w * 512;                        // + buf*8192
  u16* vd0 = kvs + 4096 + w * 512;                 // + buf*8192

  // Q as B-fragments: lane holds Q[q0w+l31][dstep*16 + hi*8 .. +7]
  bf16x8 qf[4];
#pragma unroll
  for (int dstep = 0; dstep < 4; ++dstep)
    qf[dstep] = ld_bf8(qb + base + (size_t)(q0w + l31) * 64 + dstep * 16 + hi * 8);

  f32x16 o[2];   // O^T accum: d = dh*32 + (r&3)+8*(r>>2)+4*hi, q = l31
#pragma unroll
  for (int dh = 0; dh < 2; ++dh)
#pragma unroll
    for (int r = 0; r < 16; ++r) o[dh][r] = 0.f;
  float ps = 0.f;

  // prologue: stage tile 0 into buffer 0
  glds16(kg0, kd0);
  glds16(kg0 + 32 * 64, kd0 + 2048);
  glds16(vg0, vd0);
  glds16(vg0 + 32 * 1024, vd0 + 2048);
  __syncthreads();

  for (int kt = 0; kt < 16; ++kt) {
    const int cur = kt & 1;
    if (kt < 15) {   // async prefetch next tile into the other buffer
      const int nxt = cur ^ 1;
      glds16(kg0 + (kt + 1) * 4096, kd0 + nxt * 8192);
      glds16(kg0 + (kt + 1) * 4096 + 32 * 64, kd0 + nxt * 8192 + 2048);
      glds16(vg0 + (kt + 1) * 64, vd0 + nxt * 8192);
      glds16(vg0 + (kt + 1) * 64 + 32 * 1024, vd0 + nxt * 8192 + 2048);
    }

    const u16* Kl = kvs + cur * 8192;
    const u16* Vl = kvs + cur * 8192 + 4096;

#pragma unroll
    for (int kk = 0; kk < 2; ++kk) {
      f32x16 s;
#pragma unroll
      for (int r = 0; r < 16; ++r) s[r] = 0.f;
      const int rk = kk * 32 + l31;
      __builtin_amdgcn_s_setprio(1);
#pragma unroll
      for (int dstep = 0; dstep < 4; ++dstep) {
        bf16x8 kf = ld_bf8(Kl + rk * 64 + ((dstep * 2 + hi) ^ (rk & 7)) * 8);
        s = __builtin_amdgcn_mfma_f32_32x32x16_bf16(kf, qf[dstep], s, 0, 0, 0);
      }
      __builtin_amdgcn_s_setprio(0);
      // s[g*4+i] holds S^T at k_local = kk*32 + 8g + 4hi + i, q = l31
#pragma unroll
      for (int g = 0; g < 4; ++g) {
        f32x4 bv = *(const f32x4*)(mbias + kt * 64 + kk * 32 + g * 8 + hi * 4);
        float p0 = fexp2(s[g * 4 + 0] + bv[0]);
        float p1 = fexp2(s[g * 4 + 1] + bv[1]);
        float p2 = fexp2(s[g * 4 + 2] + bv[2]);
        float p3 = fexp2(s[g * 4 + 3] + bv[3]);
        ps += (p0 + p1) + (p2 + p3);
        const int colb = g * 8 + hi * 4;
        *(u32*)&plds[w][l31][colb]     = cvtpk(p0, p1);
        *(u32*)&plds[w][l31][colb + 2] = cvtpk(p2, p3);
      }

      // PV for this kk: O^T += V^T * P^T
      __builtin_amdgcn_s_setprio(1);
#pragma unroll
      for (int t = 0; t < 2; ++t) {
        bf16x8 pf = ld_bf8(&plds[w][l31][t * 16 + hi * 8]);
#pragma unroll
        for (int dh = 0; dh < 2; ++dh) {
          const int rv = dh * 32 + l31;
          const int gv = kk * 4 + t * 2 + hi;
          bf16x8 vf = ld_bf8(Vl + rv * 64 + (gv ^ (rv & 7)) * 8);
          o[dh] = __builtin_amdgcn_mfma_f32_32x32x16_bf16(vf, pf, o[dh], 0, 0, 0);
        }
      }
      __builtin_amdgcn_s_setprio(0);
    }

    __syncthreads();   // staged kt+1 complete; safe to swap buffers
  }

  // row sum split across hi halves: one swap-add, then normalize
  ps += __shfl_xor(ps, 32, 64);
  float inv = 1.0f / ps;

  // stage normalized O^T (bf16) into kvs (free now), rows = q, cols = d
  u16* obuf = kvs + w * 2304;   // [32][72] per wave
#pragma unroll
  for (int dh = 0; dh < 2; ++dh)
#pragma unroll
    for (int j = 0; j < 8; ++j) {
      u32 v = cvtpk(o[dh][2 * j] * inv, o[dh][2 * j + 1] * inv);
      int col = dh * 32 + 8 * (j >> 1) + 4 * hi + 2 * (j & 1);
      *(u32*)(obuf + l31 * 72 + col) = v;
    }

  // coalesced readback: lane covers half a q-row (32 d)
  {
    int row2 = lane >> 1, ch = lane & 1;
    const u16* srcp = obuf + row2 * 72 + ch * 32;
    u16x8 t0 = *(const u16x8*)(srcp);
    u16x8 t1 = *(const u16x8*)(srcp + 8);
    u16x8 t2 = *(const u16x8*)(srcp + 16);
    u16x8 t3 = *(const u16x8*)(srcp + 24);
    size_t m = (size_t)b * 1024 + qt * 128 + w * 32 + row2;
    u16* dst = x2 + m * 768 + h * 64 + ch * 32;
    *(u16x8*)dst = t0;
    *(u16x8*)(dst + 8) = t1;
    *(u16x8*)(dst + 16) = t2;
    *(u16x8*)(dst + 24) = t3;
  }
}

// ---------------------------------------------------------------- out proj
// R9/R11 best out_gemm: BK=64 double-buffered counted vmcnt; grid 384 =
// 8 XCD x (8 by x 6 bx).
__global__ __launch_bounds__(256, 2)
void out_gemm(const u16* __restrict__ A, const u16* __restrict__ W,
              const float* __restrict__ bias, float* __restrict__ out) {
  __shared__ __align__(16) u16 lA[2][128 * 64];
  __shared__ __align__(16) u16 lB[2][128 * 64];
  const int tid = threadIdx.x;
  const int lane = tid & 63, wid = tid >> 6;
  const int wm = wid >> 1, wn = wid & 1;
  const int l15 = lane & 15, l4 = lane >> 4;
  const int h7 = l15 & 7;

  const int p = blockIdx.x;
  const int xcd = p & 7, i = p >> 3;
  const int by = xcd * 8 + i / 6;
  const int bx = i % 6;
  const int rowA0 = by * 128, rowB0 = bx * 128;

  const int rlo = lane >> 3;
  const int swz = (lane & 7) ^ rlo;
  const u16* ga = A + (size_t)(rowA0 + wid * 8 + rlo) * 768 + swz * 8;
  const u16* gb = W + (size_t)(rowB0 + wid * 8 + rlo) * 768 + swz * 8;

  f32x4 acc[4][4];
  const f32x4 vz = {0.f, 0.f, 0.f, 0.f};
#pragma unroll
  for (int ii = 0; ii < 4; ++ii)
#pragma unroll
    for (int j = 0; j < 4; ++j) acc[ii][j] = vz;

#define OSTAGE(buf, k0)                                          \
  {                                                              \
    _Pragma("unroll") for (int j = 0; j < 4; ++j) {              \
      glds16(ga + (k0) + j * 32 * 768, lA[buf] + j * 2048 + wid * 512); \
      glds16(gb + (k0) + j * 32 * 768, lB[buf] + j * 2048 + wid * 512); \
    }                                                            \
  }

  OSTAGE(0, 0);

  for (int ks = 0; ks < 12; ++ks) {
    const int cur = ks & 1;
    __builtin_amdgcn_s_barrier();
    if (ks < 11) {
      OSTAGE(cur ^ 1, (ks + 1) * 64);
      asm volatile("s_waitcnt vmcnt(8)" ::: "memory");
    } else {
      asm volatile("s_waitcnt vmcnt(0)" ::: "memory");
    }
    __builtin_amdgcn_s_barrier();
    __builtin_amdgcn_sched_barrier(0);

    bf16x8 af[4][2], bfr[4][2];
#pragma unroll
    for (int mi = 0; mi < 4; ++mi)
#pragma unroll
      for (int kk = 0; kk < 2; ++kk)
        af[mi][kk] = ld_bf8(lA[cur] + (wm * 64 + mi * 16 + l15) * 64 +
                            (((kk * 4 + l4) ^ h7) * 8));
#pragma unroll
    for (int ni = 0; ni < 4; ++ni)
#pragma unroll
      for (int kk = 0; kk < 2; ++kk)
        bfr[ni][kk] = ld_bf8(lB[cur] + (wn * 64 + ni * 16 + l15) * 64 +
                             (((kk * 4 + l4) ^ h7) * 8));
    __builtin_amdgcn_s_setprio(1);
#pragma unroll
    for (int mi = 0; mi < 4; ++mi)
#pragma unroll
      for (int ni = 0; ni < 4; ++ni)
#pragma unroll
        for (int kk = 0; kk < 2; ++kk)
          acc[mi][ni] = __builtin_amdgcn_mfma_f32_16x16x32_bf16(
              af[mi][kk], bfr[ni][kk], acc[mi][ni], 0, 0, 0);
    __builtin_amdgcn_s_setprio(0);
  }
#undef OSTAGE

#pragma unroll
  for (int ni = 0; ni < 4; ++ni) {
    int n = rowB0 + wn * 64 + ni * 16 + l15;
    float bn_ = bias[n];
#pragma unroll
    for (int mi = 0; mi < 4; ++mi)
#pragma unroll
      for (int r = 0; r < 4; ++r) {
        int m = rowA0 + wm * 64 + mi * 16 + l4 * 4 + r;
        out[(size_t)m * 768 + n] = acc[mi][ni][r] + bn_;
      }
  }
}

// ---------------------------------------------------------------- launch
extern "C" void kernel_launch(void* const* d_in, const int* in_sizes, int n_in,
                              void* d_out, int out_size, void* d_ws, size_t ws_size,
                              hipStream_t stream) {
  const float* x    = (const float*)d_in[0];
  const void*  mask = d_in[1];
  const float* wqkv = (const float*)d_in[2];
  const float* bqkv = (const float*)d_in[3];
  const float* wo   = (const float*)d_in[4];
  const float* bo   = (const float*)d_in[5];
  float* out = (float*)d_out;

  u16* ws = (u16*)d_ws;
  u16* xbf   = ws;
  u16* wqkvb = ws + 6291456;
  u16* wob   = ws + 8060928;
  u16* qbuf  = ws + 8650752;
  u16* kbuf  = ws + 14942208;
  u16* vtbuf = ws + 21233664;
  u16* x2buf = ws + 27525120;

  convert_kernel<<<2048, 256, 0, stream>>>(x, wqkv, wo, xbf, wqkvb, wob);
  qkv_gemm<<<768, 256, 0, stream>>>(xbf, wqkvb, bqkv, qbuf, kbuf, vtbuf);
  attn_kernel<<<dim3(96, 8), 256, 0, stream>>>(qbuf, kbuf, vtbuf, mask, x2buf);
  out_gemm<<<384, 256, 0, stream>>>(x2buf, wob, bo, out);
}